// Round 3
// baseline (27.575 us; speedup 1.0000x reference)
//
#include <hip/hip_runtime.h>
#include <math.h>

#define NBINS 256

typedef float fx4 __attribute__((ext_vector_type(4)));  // native vec: OK for nontemporal builtins

// One block per batch row, 256 threads.
// Knots staged as three b32 LDS arrays (x, t, slope) -> conflict-light random
// access (bank = idx % 32, ~2-way avg = free). Slope precomputed per segment
// so the per-element eval is: read s_x[k] -> pick segment s -> fma with
// s_x[s], s_t[s], s_m[s]. Query loop is 4-deep unrolled (4x 16B loads in
// flight per thread) with nontemporal load/store on the streamed arrays.
__global__ __launch_bounds__(256) void pwl_kernel(
    const float* __restrict__ inp,   // [B, 256, 2] interleaved (p0, p1)
    const float* __restrict__ x,     // [B, nq]
    float* __restrict__ out,         // [B, nq]
    int nq)
{
    __shared__ float s_x[NBINS];
    __shared__ float s_t[NBINS];
    __shared__ float s_m[NBINS];     // slope of segment [j, j+1], j in [0,254]

    const int b   = blockIdx.x;
    const int tid = threadIdx.x;

    // ---- stage knots ----
    float2 p = ((const float2*)inp)[(size_t)b * NBINS + tid];
    float xa = ((float)tid + 0.5f) * (1.0f / 256.0f)
             + tanhf(p.x) * (0.5f / 256.0f);
    xa = fminf(fmaxf(xa, 0.0f), 1.0f);
    s_x[tid] = xa;
    s_t[tid] = p.y;
    __syncthreads();
    if (tid < NBINS - 1) {
        // knots are strictly increasing (each strictly inside its bin)
        s_m[tid] = (s_t[tid + 1] - s_t[tid]) / (s_x[tid + 1] - s_x[tid]);
    }
    __syncthreads();

    // ---- per-element eval ----
    auto evalf = [&](float xi) -> float {
        int k = (int)(xi * 256.0f);          // exact pow2 scale, xi in [0,1)
        k = min(max(k, 0), NBINS - 1);
        float xk = s_x[k];
        int s = (xi >= xk) ? k : k - 1;      // segment index
        s = min(max(s, 0), NBINS - 2);       // clamps double as extrapolation
        return fmaf(xi - s_x[s], s_m[s], s_t[s]);
    };
    auto eval4 = [&](fx4 q) -> fx4 {
        fx4 r;
        r.x = evalf(q.x); r.y = evalf(q.y);
        r.z = evalf(q.z); r.w = evalf(q.w);
        return r;
    };

    const fx4* xrow = (const fx4*)(x + (size_t)b * nq);
    fx4*       orow = (fx4*)(out + (size_t)b * nq);
    const int nvec = nq >> 2;

    int i = tid;
    // 4-deep unrolled main loop: all 4 HBM loads issued before any compute.
    for (; i + 768 < nvec; i += 1024) {
        fx4 q0 = __builtin_nontemporal_load(&xrow[i]);
        fx4 q1 = __builtin_nontemporal_load(&xrow[i + 256]);
        fx4 q2 = __builtin_nontemporal_load(&xrow[i + 512]);
        fx4 q3 = __builtin_nontemporal_load(&xrow[i + 768]);
        fx4 r0 = eval4(q0);
        fx4 r1 = eval4(q1);
        fx4 r2 = eval4(q2);
        fx4 r3 = eval4(q3);
        __builtin_nontemporal_store(r0, &orow[i]);
        __builtin_nontemporal_store(r1, &orow[i + 256]);
        __builtin_nontemporal_store(r2, &orow[i + 512]);
        __builtin_nontemporal_store(r3, &orow[i + 768]);
    }
    // remainder (not taken for nq = 4096)
    for (; i < nvec; i += 256) {
        fx4 q = __builtin_nontemporal_load(&xrow[i]);
        fx4 r = eval4(q);
        __builtin_nontemporal_store(r, &orow[i]);
    }
}

extern "C" void kernel_launch(void* const* d_in, const int* in_sizes, int n_in,
                              void* d_out, int out_size, void* d_ws, size_t ws_size,
                              hipStream_t stream)
{
    const float* inp = (const float*)d_in[0];   // [B, 256, 2]
    const float* x   = (const float*)d_in[1];   // [B, nq]
    float*       out = (float*)d_out;           // [B, nq]

    const int B  = in_sizes[0] / (2 * NBINS);
    const int nq = in_sizes[1] / B;             // 4096, divisible by 4

    pwl_kernel<<<B, 256, 0, stream>>>(inp, x, out, nq);
}

// Round 4
// 26.991 us; speedup vs baseline: 1.0216x; 1.0216x over previous
//
#include <hip/hip_runtime.h>
#include <math.h>

#define NBINS 256

typedef float fx4 __attribute__((ext_vector_type(4)));

// One block per batch row, 256 threads.
// Per-bin LDS table: {x_k, t_k, m_{k-1}, m_k} (4 KB). Knot k lies strictly
// inside bin k, so for xi in bin k the containing segment is k (xi>=x_k) or
// k-1 (xi<x_k); knot k is an endpoint of BOTH, so anchoring at knot k is
// exact either way: y = t_k + (xi-x_k)*m_sel. Edge bins duplicate the end
// slope, which yields jnp.interp's "extrapolate" semantics for free.
// => exactly ONE ds_read_b128 + ~8 VALU per element.
__global__ __launch_bounds__(256) void pwl_kernel(
    const float* __restrict__ inp,   // [B, 256, 2] interleaved (p0, p1)
    const float* __restrict__ x,     // [B, nq]
    float* __restrict__ out,         // [B, nq]
    int nq)
{
    __shared__ float s_x[NBINS];
    __shared__ float s_t[NBINS];
    __shared__ fx4   s_tab[NBINS];   // {x_k, t_k, m_lo, m_hi}

    const int b   = blockIdx.x;
    const int tid = threadIdx.x;

    // ---- stage knots ----
    float2 p = ((const float2*)inp)[(size_t)b * NBINS + tid];
    float xa = ((float)tid + 0.5f) * (1.0f / 256.0f)
             + tanhf(p.x) * (0.5f / 256.0f);
    xa = fminf(fmaxf(xa, 0.0f), 1.0f);
    s_x[tid] = xa;
    s_t[tid] = p.y;
    __syncthreads();

    // ---- build per-bin table ----
    {
        const int im1 = max(tid - 1, 0), ip1 = min(tid + 1, NBINS - 1);
        float xm1 = s_x[im1], tm1 = s_t[im1];
        float xp1 = s_x[ip1], tp1 = s_t[ip1];
        // knots strictly increasing -> no div-by-0 on the taken side
        float mLr = (p.y - tm1) / (xa - xm1);   // slope of segment [tid-1, tid]
        float mHr = (tp1 - p.y) / (xp1 - xa);   // slope of segment [tid, tid+1]
        float mLo = (tid > 0)         ? mLr : mHr;
        float mHi = (tid < NBINS - 1) ? mHr : mLr;
        fx4 e; e.x = xa; e.y = p.y; e.z = mLo; e.w = mHi;
        s_tab[tid] = e;
    }
    __syncthreads();

    // ---- per-element eval: 1 LDS b128 read + select + fma ----
    auto evalf = [&](float xi) -> float {
        int k = (int)(xi * 256.0f);          // exact pow2 scale, xi in [0,1)
        k = min(max(k, 0), NBINS - 1);
        fx4 e = s_tab[k];
        float m = (xi >= e.x) ? e.w : e.z;
        return fmaf(xi - e.x, m, e.y);
    };
    auto eval4 = [&](fx4 q) -> fx4 {
        fx4 r;
        r.x = evalf(q.x); r.y = evalf(q.y);
        r.z = evalf(q.z); r.w = evalf(q.w);
        return r;
    };

    const fx4* xrow = (const fx4*)(x + (size_t)b * nq);
    fx4*       orow = (fx4*)(out + (size_t)b * nq);
    const int nvec = nq >> 2;

    int i = tid;
    // 4-deep unrolled main loop: all 4 HBM loads issued before any compute.
    for (; i + 768 < nvec; i += 1024) {
        fx4 q0 = __builtin_nontemporal_load(&xrow[i]);
        fx4 q1 = __builtin_nontemporal_load(&xrow[i + 256]);
        fx4 q2 = __builtin_nontemporal_load(&xrow[i + 512]);
        fx4 q3 = __builtin_nontemporal_load(&xrow[i + 768]);
        fx4 r0 = eval4(q0);
        fx4 r1 = eval4(q1);
        fx4 r2 = eval4(q2);
        fx4 r3 = eval4(q3);
        __builtin_nontemporal_store(r0, &orow[i]);
        __builtin_nontemporal_store(r1, &orow[i + 256]);
        __builtin_nontemporal_store(r2, &orow[i + 512]);
        __builtin_nontemporal_store(r3, &orow[i + 768]);
    }
    // remainder (not taken for nq = 4096)
    for (; i < nvec; i += 256) {
        fx4 q = __builtin_nontemporal_load(&xrow[i]);
        fx4 r = eval4(q);
        __builtin_nontemporal_store(r, &orow[i]);
    }
}

extern "C" void kernel_launch(void* const* d_in, const int* in_sizes, int n_in,
                              void* d_out, int out_size, void* d_ws, size_t ws_size,
                              hipStream_t stream)
{
    const float* inp = (const float*)d_in[0];   // [B, 256, 2]
    const float* x   = (const float*)d_in[1];   // [B, nq]
    float*       out = (float*)d_out;           // [B, nq]

    const int B  = in_sizes[0] / (2 * NBINS);
    const int nq = in_sizes[1] / B;             // 4096, divisible by 4

    pwl_kernel<<<B, 256, 0, stream>>>(inp, x, out, nq);
}